// Round 24
// baseline (108.054 us; speedup 1.0000x reference)
//
#include <hip/hip_runtime.h>

#define NV 1084
#define NVPAD 1088
#define SCW 1088

typedef __attribute__((ext_vector_type(8))) short short8v;
typedef __attribute__((ext_vector_type(4))) float f32x4;

__device__ inline unsigned short f2bf(float f) {
    unsigned int u = __float_as_uint(f);
    unsigned int r = (u + 0x7FFFu + ((u >> 16) & 1u)) >> 16;
    return (unsigned short)r;
}
__device__ inline float bf2f(unsigned short h) {
    unsigned int u = ((unsigned int)h) << 16;
    return __uint_as_float(u);
}

// ws layout (all written by D1, read by D2):
//  euler_ws : B*45 f32
//  Mfinal   : 1344 f32     M[21][16][4]
//  Gbf      : NVPAD*64 u16 G[v][4k+d] = w[v][k]*{vx,vy,vz,1}[d] (bf16)

__device__ inline void rodrigues9(float x, float y, float z, float R[9]) {
    float n2 = x * x + y * y + z * z + 1e-8f;
    float angle = sqrtf(n2);
    float inv = 1.0f / angle;
    float ax = x * inv, ay = y * inv, az = z * inv;
    float c = __cosf(angle), s = __sinf(angle);
    float C = 1.0f - c;
    R[0] = 1.0f - C * (ay * ay + az * az);
    R[1] = -s * az + C * ax * ay;
    R[2] = s * ay + C * ax * az;
    R[3] = s * az + C * ax * ay;
    R[4] = 1.0f - C * (ax * ax + az * az);
    R[5] = -s * ax + C * ay * az;
    R[6] = -s * ay + C * ax * az;
    R[7] = s * ax + C * ay * az;
    R[8] = 1.0f - C * (ax * ax + ay * ay);
}

// D1: blocks [0,nE): euler. [nE,nE+336): Mfinal direct-wide. [nE+336,+272): Gbf.
__global__ __launch_bounds__(256) void prep_kernel(
    const float* __restrict__ theta, const float* __restrict__ hc,
    const float* __restrict__ hm, const float* __restrict__ vt,
    const float* __restrict__ jreg, const float* __restrict__ wts,
    float* __restrict__ euler_ws, float* __restrict__ Mfinal,
    unsigned short* __restrict__ Gbf, int B, int nE) {
    int blk = blockIdx.x;
    int t = threadIdx.x;
    if (blk < nE) {
        int i = blk * 256 + t;
        if (i < B * 45) {
            int b = i / 45, col = i - b * 45;
            const float* th = theta + (size_t)b * 45;
            float acc = hm[col];
#pragma unroll
            for (int k = 0; k < 45; ++k) acc += th[k] * hc[k * 45 + col];
            euler_ws[i] = acc;
        }
    } else if (blk < nE + 336) {
        __shared__ float sm[256];
        int m = blk - nE;
        int qi = t >> 6, u = t & 63;
        int q = m * 4 + qi;             // < 1344
        int j = q >> 6, k = (q >> 2) & 15, d = q & 3;
        int v0 = u * 17, v1 = min(v0 + 17, NV);
        float acc = 0.f;
        for (int v = v0; v < v1; ++v) {
            float vh = (d == 3) ? 1.f : vt[v * 3 + d];
            acc += jreg[v * 21 + j] * wts[v * 16 + k] * vh;
        }
        sm[t] = acc;
        __syncthreads();
#pragma unroll
        for (int s = 32; s > 0; s >>= 1) {
            if (u < s) sm[t] += sm[t + s];
            __syncthreads();
        }
        if (u == 0) Mfinal[q] = sm[t];
    } else {
        int idx = (blk - nE - 336) * 256 + t;
        if (idx < NVPAD * 64) {
            int v = idx >> 6, i = idx & 63;
            int k = i >> 2, d = i & 3;
            float val = 0.f;
            if (v < NV) {
                float vh = (d == 3) ? 1.f : vt[v * 3 + d];
                val = wts[v * 16 + k] * vh;
            }
            Gbf[idx] = f2bf(val);
        }
    }
}

// D2: one block = 4 consecutive batches, fully self-contained.
__global__ __launch_bounds__(256) void verts_kernel(
    const float* __restrict__ wrist, const float* __restrict__ euler_ws,
    const float* __restrict__ Mfinal, const unsigned short* __restrict__ Gbf,
    float* __restrict__ verts, float* __restrict__ jout) {
    __shared__ float sC[12 * SCW];          // 52224 B
    __shared__ unsigned short sAb[16 * 64]; // 2048 B (rows 12-15 zero)
    __shared__ float sj[48];

    int t = threadIdx.x;
    int b0 = blockIdx.x * 4;
    int w = t >> 6, lane = t & 63;
    int lrow = lane & 15, lk = lane >> 4;

    // phase 0
    if (t < 48) {
        int j = t / 3, c = t - 3 * (t / 3);
        float acc = 0.f;
#pragma unroll
        for (int k = 0; k < 16; ++k) acc += Mfinal[j * 64 + k * 4 + c];
        sj[t] = acc;
    }
    sAb[768 + t] = 0;                       // rows 12..15
    __syncthreads();

    // phase 1: FK
    if (t < 20) {
        int bl = t / 5, r = t - 5 * bl;
        int b = b0 + bl;
        float e[9];
#pragma unroll
        for (int col = 0; col < 9; ++col)
            e[col] = euler_ws[(size_t)b * 45 + 9 * r + col];

        float R[9];
        rodrigues9(wrist[b * 3 + 0], wrist[b * 3 + 1], wrist[b * 3 + 2], R);
        float J0x = sj[0], J0y = sj[1], J0z = sj[2];
        float Ap[12];
        Ap[0] = R[0]; Ap[1] = R[1]; Ap[2] = R[2]; Ap[3] = J0x;
        Ap[4] = R[3]; Ap[5] = R[4]; Ap[6] = R[5]; Ap[7] = J0y;
        Ap[8] = R[6]; Ap[9] = R[7]; Ap[10] = R[8]; Ap[11] = J0z;
        if (r == 0) {
#pragma unroll
            for (int row = 0; row < 3; ++row) {
                float a0 = Ap[row * 4 + 0], a1 = Ap[row * 4 + 1], a2 = Ap[row * 4 + 2];
                float a3 = Ap[row * 4 + 3] - (a0 * J0x + a1 * J0y + a2 * J0z);
                unsigned short* dst = &sAb[(bl * 3 + row) * 64];
                dst[0] = f2bf(a0); dst[1] = f2bf(a1);
                dst[2] = f2bf(a2); dst[3] = f2bf(a3);
            }
        }
        float px = J0x, py = J0y, pz = J0z;
#pragma unroll
        for (int s = 0; s < 3; ++s) {
            int i = r * 3 + s + 1;
            rodrigues9(e[3 * s + 0], e[3 * s + 1], e[3 * s + 2], R);
            float jx = sj[i * 3 + 0], jy = sj[i * 3 + 1], jz = sj[i * 3 + 2];
            float tx = jx - px, ty = jy - py, tz = jz - pz;
            float An[12];
#pragma unroll
            for (int row = 0; row < 3; ++row) {
                An[row * 4 + 0] = Ap[row * 4 + 0] * R[0] + Ap[row * 4 + 1] * R[3] + Ap[row * 4 + 2] * R[6];
                An[row * 4 + 1] = Ap[row * 4 + 0] * R[1] + Ap[row * 4 + 1] * R[4] + Ap[row * 4 + 2] * R[7];
                An[row * 4 + 2] = Ap[row * 4 + 0] * R[2] + Ap[row * 4 + 1] * R[5] + Ap[row * 4 + 2] * R[8];
                An[row * 4 + 3] = Ap[row * 4 + 3] + Ap[row * 4 + 0] * tx + Ap[row * 4 + 1] * ty + Ap[row * 4 + 2] * tz;
            }
#pragma unroll
            for (int row = 0; row < 3; ++row) {
                float a0 = An[row * 4 + 0], a1 = An[row * 4 + 1], a2 = An[row * 4 + 2];
                float a3 = An[row * 4 + 3] - (a0 * jx + a1 * jy + a2 * jz);
                unsigned short* dst = &sAb[(bl * 3 + row) * 64 + 4 * i];
                dst[0] = f2bf(a0); dst[1] = f2bf(a1);
                dst[2] = f2bf(a2); dst[3] = f2bf(a3);
            }
#pragma unroll
            for (int q = 0; q < 12; ++q) Ap[q] = An[q];
            px = jx; py = jy; pz = jz;
        }
    }
    __syncthreads();

    // phase 2: MFMA sweep
    short8v a0 = *(const short8v*)&sAb[lrow * 64 + lk * 8];
    short8v a1 = *(const short8v*)&sAb[lrow * 64 + lk * 8 + 32];
    for (int vt4 = w; vt4 < NVPAD / 16; vt4 += 4) {
        int v = vt4 * 16 + lrow;
        const unsigned short* Br = Gbf + (size_t)v * 64 + lk * 8;
        short8v g0 = *(const short8v*)Br;
        short8v g1 = *(const short8v*)(Br + 32);
        f32x4 acc = {0.f, 0.f, 0.f, 0.f};
        acc = __builtin_amdgcn_mfma_f32_16x16x32_bf16(a0, g0, acc, 0, 0, 0);
        acc = __builtin_amdgcn_mfma_f32_16x16x32_bf16(a1, g1, acc, 0, 0, 0);
        if (lk < 3) {
            float* dst = &sC[(lk * 4) * SCW + vt4 * 16 + lrow];
#pragma unroll
            for (int q = 0; q < 4; ++q) dst[q * SCW] = acc[q];
        }
    }
    __syncthreads();

    // phase 3: contiguous NT stream (4 batches x 813 f32x4 = 52 KB)
    float* outp = verts + (size_t)b0 * (NV * 3);
#pragma unroll 1
    for (int f = t; f < 3252; f += 256) {
        int bl = f / 813;
        int off = (f - bl * 813) * 4;
        f32x4 val;
#pragma unroll
        for (int j = 0; j < 4; ++j) {
            int o = off + j;
            int v_ = o / 3, p_ = o - v_ * 3;
            val[j] = sC[(bl * 3 + p_) * SCW + v_];
        }
        __builtin_nontemporal_store(val, (f32x4*)(outp + (size_t)f * 4));
    }

    // phase 4: joints for the 4 batches
    if (t < 252) {
        int bl = t / 63;
        int rem = t - bl * 63;
        int j = rem / 3;
        int c = rem - j * 3;
        const unsigned short* Ar = &sAb[(bl * 3 + c) * 64];
        const float* Mj = Mfinal + j * 64;
        float acc = 0.f;
#pragma unroll
        for (int k = 0; k < 16; ++k) {
            float4 m = *(const float4*)&Mj[k * 4];
            acc += bf2f(Ar[k * 4 + 0]) * m.x + bf2f(Ar[k * 4 + 1]) * m.y +
                   bf2f(Ar[k * 4 + 2]) * m.z + bf2f(Ar[k * 4 + 3]) * m.w;
        }
        __builtin_nontemporal_store(acc, jout + (size_t)(b0 + bl) * 63 + rem);
    }
}

extern "C" void kernel_launch(void* const* d_in, const int* in_sizes, int n_in,
                              void* d_out, int out_size, void* d_ws, size_t ws_size,
                              hipStream_t stream) {
    const float* theta = (const float*)d_in[1];
    const float* wrist = (const float*)d_in[2];
    const float* vtpl  = (const float*)d_in[3];
    const float* jreg  = (const float*)d_in[4];
    const float* hc    = (const float*)d_in[5];
    const float* hm    = (const float*)d_in[6];
    const float* wts   = (const float*)d_in[7];
    int B = in_sizes[1] / 45;  // 4096

    float* euler_ws = (float*)d_ws;                       // B*45 f32
    float* Mfinal   = euler_ws + (size_t)B * 45;          // 1344 f32
    unsigned short* Gbf = (unsigned short*)(Mfinal + 1344);  // NVPAD*64 u16
    float* verts  = (float*)d_out;
    float* jout   = verts + (size_t)B * NV * 3;

    int nE = (B * 45 + 255) / 256;   // 720
    prep_kernel<<<nE + 336 + 272, 256, 0, stream>>>(
        theta, hc, hm, vtpl, jreg, wts, euler_ws, Mfinal, Gbf, B, nE);
    // MEASUREMENT ROUND #2: D2 launched 3x (idempotent — reads only ws/inputs,
    // writes verts/jout deterministically). D2_warm = (dur_us - 48.15) / 2.
    for (int rep = 0; rep < 3; ++rep) {
        verts_kernel<<<B / 4, 256, 0, stream>>>(
            wrist, euler_ws, Mfinal, Gbf, verts, jout);
    }
}

// Round 25
// 51.811 us; speedup vs baseline: 2.0855x; 2.0855x over previous
//
#include <hip/hip_runtime.h>

#define NV 1084
#define NVPAD 1088

typedef __attribute__((ext_vector_type(8))) short short8v;
typedef __attribute__((ext_vector_type(4))) float f32x4;

__device__ inline unsigned short f2bf(float f) {
    unsigned int u = __float_as_uint(f);
    unsigned int r = (u + 0x7FFFu + ((u >> 16) & 1u)) >> 16;
    return (unsigned short)r;
}
__device__ inline float bf2f(unsigned short h) {
    unsigned int u = ((unsigned int)h) << 16;
    return __uint_as_float(u);
}

// ws layout:
//  Mfinal : 1344 f32       M[21][16][4]
//  Gbf    : NVPAD*64 u16   G[v][4k+d] = w[v][k]*{vx,vy,vz,1}[d] (bf16)

__device__ inline void rodrigues9(float x, float y, float z, float R[9]) {
    float n2 = x * x + y * y + z * z + 1e-8f;
    float angle = sqrtf(n2);
    float inv = 1.0f / angle;
    float ax = x * inv, ay = y * inv, az = z * inv;
    float c = __cosf(angle), s = __sinf(angle);
    float C = 1.0f - c;
    R[0] = 1.0f - C * (ay * ay + az * az);
    R[1] = -s * az + C * ax * ay;
    R[2] = s * ay + C * ax * az;
    R[3] = s * az + C * ax * ay;
    R[4] = 1.0f - C * (ax * ax + az * az);
    R[5] = -s * ax + C * ay * az;
    R[6] = -s * ay + C * ax * az;
    R[7] = s * ax + C * ay * az;
    R[8] = 1.0f - C * (ax * ax + ay * ay);
}

// D1: blocks [0,336): Mfinal direct-wide. [336,336+272): Gbf. No euler.
__global__ __launch_bounds__(256) void prep_kernel(
    const float* __restrict__ vt, const float* __restrict__ jreg,
    const float* __restrict__ wts, float* __restrict__ Mfinal,
    unsigned short* __restrict__ Gbf) {
    int blk = blockIdx.x;
    int t = threadIdx.x;
    if (blk < 336) {
        __shared__ float sm[256];
        int qi = t >> 6, u = t & 63;
        int q = blk * 4 + qi;           // < 1344
        int j = q >> 6, k = (q >> 2) & 15, d = q & 3;
        int v0 = u * 17, v1 = min(v0 + 17, NV);
        float acc = 0.f;
        for (int v = v0; v < v1; ++v) {
            float vh = (d == 3) ? 1.f : vt[v * 3 + d];
            acc += jreg[v * 21 + j] * wts[v * 16 + k] * vh;
        }
        sm[t] = acc;
        __syncthreads();
#pragma unroll
        for (int s = 32; s > 0; s >>= 1) {
            if (u < s) sm[t] += sm[t + s];
            __syncthreads();
        }
        if (u == 0) Mfinal[q] = sm[t];
    } else {
        int idx = (blk - 336) * 256 + t;
        if (idx < NVPAD * 64) {
            int v = idx >> 6, i = idx & 63;
            int k = i >> 2, d = i & 3;
            float val = 0.f;
            if (v < NV) {
                float vh = (d == 3) ? 1.f : vt[v * 3 + d];
                val = wts[v * 16 + k] * vh;
            }
            Gbf[idx] = f2bf(val);
        }
    }
}

// D2: one block = 4 consecutive batches. Tiny LDS (2.3 KB) -> 8 blocks/CU,
// whole grid co-resident in 0.5 rounds.
//   phase0: sj[48] from Mfinal; zero sAb pad rows
//   phase1: FK inline (20 threads), euler computed per-thread (9 cols, hc L2)
//   phase2: MFMA sweep; C-fragments stored DIRECTLY to global (R12 pattern)
//   phase3: joints from sAb x Mfinal
__global__ __launch_bounds__(256) void verts_kernel(
    const float* __restrict__ theta, const float* __restrict__ wrist,
    const float* __restrict__ hc, const float* __restrict__ hm,
    const float* __restrict__ euler_unused, const float* __restrict__ Mfinal,
    const unsigned short* __restrict__ Gbf,
    float* __restrict__ verts, float* __restrict__ jout) {
    __shared__ unsigned short sAb[16 * 64]; // bf16 A rows (12 valid + 4 zero)
    __shared__ float sj[48];

    int t = threadIdx.x;
    int b0 = blockIdx.x * 4;
    int w = t >> 6, lane = t & 63;
    int lrow = lane & 15, lk = lane >> 4;

    // phase 0
    if (t < 48) {
        int j = t / 3, c = t - 3 * (t / 3);
        float acc = 0.f;
#pragma unroll
        for (int k = 0; k < 16; ++k) acc += Mfinal[j * 64 + k * 4 + c];
        sj[t] = acc;
    }
    sAb[768 + t] = 0;                       // rows 12..15
    __syncthreads();

    // phase 1: FK (inline euler)
    if (t < 20) {
        int bl = t / 5, r = t - 5 * bl;
        int b = b0 + bl;
        // euler cols [9r, 9r+9) for this thread
        float e[9];
        {
            const float* th = theta + (size_t)b * 45;
            int base = 9 * r;
#pragma unroll
            for (int col = 0; col < 9; ++col) e[col] = hm[base + col];
            for (int k = 0; k < 45; ++k) {
                float tk = th[k];
                const float* hck = hc + k * 45 + base;
#pragma unroll
                for (int col = 0; col < 9; ++col) e[col] += tk * hck[col];
            }
        }

        float R[9];
        rodrigues9(wrist[b * 3 + 0], wrist[b * 3 + 1], wrist[b * 3 + 2], R);
        float J0x = sj[0], J0y = sj[1], J0z = sj[2];
        float Ap[12];
        Ap[0] = R[0]; Ap[1] = R[1]; Ap[2] = R[2]; Ap[3] = J0x;
        Ap[4] = R[3]; Ap[5] = R[4]; Ap[6] = R[5]; Ap[7] = J0y;
        Ap[8] = R[6]; Ap[9] = R[7]; Ap[10] = R[8]; Ap[11] = J0z;
        if (r == 0) {
#pragma unroll
            for (int row = 0; row < 3; ++row) {
                float a0 = Ap[row * 4 + 0], a1 = Ap[row * 4 + 1], a2 = Ap[row * 4 + 2];
                float a3 = Ap[row * 4 + 3] - (a0 * J0x + a1 * J0y + a2 * J0z);
                unsigned short* dst = &sAb[(bl * 3 + row) * 64];
                dst[0] = f2bf(a0); dst[1] = f2bf(a1);
                dst[2] = f2bf(a2); dst[3] = f2bf(a3);
            }
        }
        float px = J0x, py = J0y, pz = J0z;
#pragma unroll
        for (int s = 0; s < 3; ++s) {
            int i = r * 3 + s + 1;
            rodrigues9(e[3 * s + 0], e[3 * s + 1], e[3 * s + 2], R);
            float jx = sj[i * 3 + 0], jy = sj[i * 3 + 1], jz = sj[i * 3 + 2];
            float tx = jx - px, ty = jy - py, tz = jz - pz;
            float An[12];
#pragma unroll
            for (int row = 0; row < 3; ++row) {
                An[row * 4 + 0] = Ap[row * 4 + 0] * R[0] + Ap[row * 4 + 1] * R[3] + Ap[row * 4 + 2] * R[6];
                An[row * 4 + 1] = Ap[row * 4 + 0] * R[1] + Ap[row * 4 + 1] * R[4] + Ap[row * 4 + 2] * R[7];
                An[row * 4 + 2] = Ap[row * 4 + 0] * R[2] + Ap[row * 4 + 1] * R[5] + Ap[row * 4 + 2] * R[8];
                An[row * 4 + 3] = Ap[row * 4 + 3] + Ap[row * 4 + 0] * tx + Ap[row * 4 + 1] * ty + Ap[row * 4 + 2] * tz;
            }
#pragma unroll
            for (int row = 0; row < 3; ++row) {
                float a0 = An[row * 4 + 0], a1 = An[row * 4 + 1], a2 = An[row * 4 + 2];
                float a3 = An[row * 4 + 3] - (a0 * jx + a1 * jy + a2 * jz);
                unsigned short* dst = &sAb[(bl * 3 + row) * 64 + 4 * i];
                dst[0] = f2bf(a0); dst[1] = f2bf(a1);
                dst[2] = f2bf(a2); dst[3] = f2bf(a3);
            }
#pragma unroll
            for (int q = 0; q < 12; ++q) Ap[q] = An[q];
            px = jx; py = jy; pz = jz;
        }
    }
    __syncthreads();

    // phase 2: MFMA sweep, direct global C-fragment stores (L2-coalesced)
    short8v a0 = *(const short8v*)&sAb[lrow * 64 + lk * 8];
    short8v a1 = *(const short8v*)&sAb[lrow * 64 + lk * 8 + 32];
    // store bases: rows m = lk*4+q -> batch b0+m/3, component m%3 (lk<3 only)
    int base[4];
#pragma unroll
    for (int q = 0; q < 4; ++q) {
        int m = lk * 4 + q;             // 0..15
        int bq = m / 3, pq = m - 3 * bq;
        if (bq > 3) bq = 3;             // lk==3 rows discarded anyway
        base[q] = (b0 + bq) * (NV * 3) + pq;
    }
    for (int vt4 = w; vt4 < NVPAD / 16; vt4 += 4) {
        int v = vt4 * 16 + lrow;
        const unsigned short* Br = Gbf + (size_t)v * 64 + lk * 8;
        short8v g0 = *(const short8v*)Br;
        short8v g1 = *(const short8v*)(Br + 32);
        f32x4 acc = {0.f, 0.f, 0.f, 0.f};
        acc = __builtin_amdgcn_mfma_f32_16x16x32_bf16(a0, g0, acc, 0, 0, 0);
        acc = __builtin_amdgcn_mfma_f32_16x16x32_bf16(a1, g1, acc, 0, 0, 0);
        if (lk < 3 && v < NV) {
            int vo = v * 3;
            verts[base[0] + vo] = acc[0];
            verts[base[1] + vo] = acc[1];
            verts[base[2] + vo] = acc[2];
            verts[base[3] + vo] = acc[3];
        }
    }

    // phase 3: joints for the 4 batches (sAb valid since phase-1 barrier)
    if (t < 252) {
        int bl = t / 63;
        int rem = t - bl * 63;
        int j = rem / 3;
        int c = rem - j * 3;
        const unsigned short* Ar = &sAb[(bl * 3 + c) * 64];
        const float* Mj = Mfinal + j * 64;
        float acc = 0.f;
#pragma unroll
        for (int k = 0; k < 16; ++k) {
            float4 m = *(const float4*)&Mj[k * 4];
            acc += bf2f(Ar[k * 4 + 0]) * m.x + bf2f(Ar[k * 4 + 1]) * m.y +
                   bf2f(Ar[k * 4 + 2]) * m.z + bf2f(Ar[k * 4 + 3]) * m.w;
        }
        jout[(size_t)(b0 + bl) * 63 + rem] = acc;
    }
}

extern "C" void kernel_launch(void* const* d_in, const int* in_sizes, int n_in,
                              void* d_out, int out_size, void* d_ws, size_t ws_size,
                              hipStream_t stream) {
    const float* theta = (const float*)d_in[1];
    const float* wrist = (const float*)d_in[2];
    const float* vtpl  = (const float*)d_in[3];
    const float* jreg  = (const float*)d_in[4];
    const float* hc    = (const float*)d_in[5];
    const float* hm    = (const float*)d_in[6];
    const float* wts   = (const float*)d_in[7];
    int B = in_sizes[1] / 45;  // 4096

    float* Mfinal = (float*)d_ws;                         // 1344 f32
    unsigned short* Gbf = (unsigned short*)(Mfinal + 1344);  // NVPAD*64 u16
    float* verts  = (float*)d_out;
    float* jout   = verts + (size_t)B * NV * 3;

    prep_kernel<<<336 + 272, 256, 0, stream>>>(vtpl, jreg, wts, Mfinal, Gbf);
    verts_kernel<<<B / 4, 256, 0, stream>>>(
        theta, wrist, hc, hm, nullptr, Mfinal, Gbf, verts, jout);
}

// Round 26
// 47.983 us; speedup vs baseline: 2.2519x; 1.0798x over previous
//
#include <hip/hip_runtime.h>

#define NV 1084
#define NVPAD 1088
#define SCW 1088

typedef __attribute__((ext_vector_type(8))) short short8v;
typedef __attribute__((ext_vector_type(4))) float f32x4;

__device__ inline unsigned short f2bf(float f) {
    unsigned int u = __float_as_uint(f);
    unsigned int r = (u + 0x7FFFu + ((u >> 16) & 1u)) >> 16;
    return (unsigned short)r;
}
__device__ inline float bf2f(unsigned short h) {
    unsigned int u = ((unsigned int)h) << 16;
    return __uint_as_float(u);
}

// ws layout (all written by D1, read by D2):
//  euler_ws : B*45 f32
//  Mfinal   : 1344 f32     M[21][16][4]
//  Gbf      : NVPAD*64 u16 G[v][4k+d] = w[v][k]*{vx,vy,vz,1}[d] (bf16)

__device__ inline void rodrigues9(float x, float y, float z, float R[9]) {
    float n2 = x * x + y * y + z * z + 1e-8f;
    float angle = sqrtf(n2);
    float inv = 1.0f / angle;
    float ax = x * inv, ay = y * inv, az = z * inv;
    float c = __cosf(angle), s = __sinf(angle);
    float C = 1.0f - c;
    R[0] = 1.0f - C * (ay * ay + az * az);
    R[1] = -s * az + C * ax * ay;
    R[2] = s * ay + C * ax * az;
    R[3] = s * az + C * ax * ay;
    R[4] = 1.0f - C * (ax * ax + az * az);
    R[5] = -s * ax + C * ay * az;
    R[6] = -s * ay + C * ax * az;
    R[7] = s * ax + C * ay * az;
    R[8] = 1.0f - C * (ax * ax + ay * ay);
}

// D1: blocks [0,nE): euler. [nE,nE+336): Mfinal direct-wide. [nE+336,+272): Gbf.
__global__ __launch_bounds__(256) void prep_kernel(
    const float* __restrict__ theta, const float* __restrict__ hc,
    const float* __restrict__ hm, const float* __restrict__ vt,
    const float* __restrict__ jreg, const float* __restrict__ wts,
    float* __restrict__ euler_ws, float* __restrict__ Mfinal,
    unsigned short* __restrict__ Gbf, int B, int nE) {
    int blk = blockIdx.x;
    int t = threadIdx.x;
    if (blk < nE) {
        int i = blk * 256 + t;
        if (i < B * 45) {
            int b = i / 45, col = i - b * 45;
            const float* th = theta + (size_t)b * 45;
            float acc = hm[col];
#pragma unroll
            for (int k = 0; k < 45; ++k) acc += th[k] * hc[k * 45 + col];
            euler_ws[i] = acc;
        }
    } else if (blk < nE + 336) {
        __shared__ float sm[256];
        int m = blk - nE;
        int qi = t >> 6, u = t & 63;
        int q = m * 4 + qi;             // < 1344
        int j = q >> 6, k = (q >> 2) & 15, d = q & 3;
        int v0 = u * 17, v1 = min(v0 + 17, NV);
        float acc = 0.f;
        for (int v = v0; v < v1; ++v) {
            float vh = (d == 3) ? 1.f : vt[v * 3 + d];
            acc += jreg[v * 21 + j] * wts[v * 16 + k] * vh;
        }
        sm[t] = acc;
        __syncthreads();
#pragma unroll
        for (int s = 32; s > 0; s >>= 1) {
            if (u < s) sm[t] += sm[t + s];
            __syncthreads();
        }
        if (u == 0) Mfinal[q] = sm[t];
    } else {
        int idx = (blk - nE - 336) * 256 + t;
        if (idx < NVPAD * 64) {
            int v = idx >> 6, i = idx & 63;
            int k = i >> 2, d = i & 3;
            float val = 0.f;
            if (v < NV) {
                float vh = (d == 3) ? 1.f : vt[v * 3 + d];
                val = wts[v * 16 + k] * vh;
            }
            Gbf[idx] = f2bf(val);
        }
    }
}

// D2: one block = 4 consecutive batches, fully self-contained.
__global__ __launch_bounds__(256) void verts_kernel(
    const float* __restrict__ wrist, const float* __restrict__ euler_ws,
    const float* __restrict__ Mfinal, const unsigned short* __restrict__ Gbf,
    float* __restrict__ verts, float* __restrict__ jout) {
    __shared__ float sC[12 * SCW];          // 52224 B
    __shared__ unsigned short sAb[16 * 64]; // 2048 B (rows 12-15 zero)
    __shared__ float sj[48];

    int t = threadIdx.x;
    int b0 = blockIdx.x * 4;
    int w = t >> 6, lane = t & 63;
    int lrow = lane & 15, lk = lane >> 4;

    // phase 0
    if (t < 48) {
        int j = t / 3, c = t - 3 * (t / 3);
        float acc = 0.f;
#pragma unroll
        for (int k = 0; k < 16; ++k) acc += Mfinal[j * 64 + k * 4 + c];
        sj[t] = acc;
    }
    sAb[768 + t] = 0;                       // rows 12..15
    __syncthreads();

    // phase 1: FK
    if (t < 20) {
        int bl = t / 5, r = t - 5 * bl;
        int b = b0 + bl;
        float e[9];
#pragma unroll
        for (int col = 0; col < 9; ++col)
            e[col] = euler_ws[(size_t)b * 45 + 9 * r + col];

        float R[9];
        rodrigues9(wrist[b * 3 + 0], wrist[b * 3 + 1], wrist[b * 3 + 2], R);
        float J0x = sj[0], J0y = sj[1], J0z = sj[2];
        float Ap[12];
        Ap[0] = R[0]; Ap[1] = R[1]; Ap[2] = R[2]; Ap[3] = J0x;
        Ap[4] = R[3]; Ap[5] = R[4]; Ap[6] = R[5]; Ap[7] = J0y;
        Ap[8] = R[6]; Ap[9] = R[7]; Ap[10] = R[8]; Ap[11] = J0z;
        if (r == 0) {
#pragma unroll
            for (int row = 0; row < 3; ++row) {
                float a0 = Ap[row * 4 + 0], a1 = Ap[row * 4 + 1], a2 = Ap[row * 4 + 2];
                float a3 = Ap[row * 4 + 3] - (a0 * J0x + a1 * J0y + a2 * J0z);
                unsigned short* dst = &sAb[(bl * 3 + row) * 64];
                dst[0] = f2bf(a0); dst[1] = f2bf(a1);
                dst[2] = f2bf(a2); dst[3] = f2bf(a3);
            }
        }
        float px = J0x, py = J0y, pz = J0z;
#pragma unroll
        for (int s = 0; s < 3; ++s) {
            int i = r * 3 + s + 1;
            rodrigues9(e[3 * s + 0], e[3 * s + 1], e[3 * s + 2], R);
            float jx = sj[i * 3 + 0], jy = sj[i * 3 + 1], jz = sj[i * 3 + 2];
            float tx = jx - px, ty = jy - py, tz = jz - pz;
            float An[12];
#pragma unroll
            for (int row = 0; row < 3; ++row) {
                An[row * 4 + 0] = Ap[row * 4 + 0] * R[0] + Ap[row * 4 + 1] * R[3] + Ap[row * 4 + 2] * R[6];
                An[row * 4 + 1] = Ap[row * 4 + 0] * R[1] + Ap[row * 4 + 1] * R[4] + Ap[row * 4 + 2] * R[7];
                An[row * 4 + 2] = Ap[row * 4 + 0] * R[2] + Ap[row * 4 + 1] * R[5] + Ap[row * 4 + 2] * R[8];
                An[row * 4 + 3] = Ap[row * 4 + 3] + Ap[row * 4 + 0] * tx + Ap[row * 4 + 1] * ty + Ap[row * 4 + 2] * tz;
            }
#pragma unroll
            for (int row = 0; row < 3; ++row) {
                float a0 = An[row * 4 + 0], a1 = An[row * 4 + 1], a2 = An[row * 4 + 2];
                float a3 = An[row * 4 + 3] - (a0 * jx + a1 * jy + a2 * jz);
                unsigned short* dst = &sAb[(bl * 3 + row) * 64 + 4 * i];
                dst[0] = f2bf(a0); dst[1] = f2bf(a1);
                dst[2] = f2bf(a2); dst[3] = f2bf(a3);
            }
#pragma unroll
            for (int q = 0; q < 12; ++q) Ap[q] = An[q];
            px = jx; py = jy; pz = jz;
        }
    }
    __syncthreads();

    // phase 2: MFMA sweep
    short8v a0 = *(const short8v*)&sAb[lrow * 64 + lk * 8];
    short8v a1 = *(const short8v*)&sAb[lrow * 64 + lk * 8 + 32];
    for (int vt4 = w; vt4 < NVPAD / 16; vt4 += 4) {
        int v = vt4 * 16 + lrow;
        const unsigned short* Br = Gbf + (size_t)v * 64 + lk * 8;
        short8v g0 = *(const short8v*)Br;
        short8v g1 = *(const short8v*)(Br + 32);
        f32x4 acc = {0.f, 0.f, 0.f, 0.f};
        acc = __builtin_amdgcn_mfma_f32_16x16x32_bf16(a0, g0, acc, 0, 0, 0);
        acc = __builtin_amdgcn_mfma_f32_16x16x32_bf16(a1, g1, acc, 0, 0, 0);
        if (lk < 3) {
            float* dst = &sC[(lk * 4) * SCW + vt4 * 16 + lrow];
#pragma unroll
            for (int q = 0; q < 4; ++q) dst[q * SCW] = acc[q];
        }
    }
    __syncthreads();

    // phase 3: contiguous NT stream (4 batches x 813 f32x4 = 52 KB)
    float* outp = verts + (size_t)b0 * (NV * 3);
#pragma unroll 1
    for (int f = t; f < 3252; f += 256) {
        int bl = f / 813;
        int off = (f - bl * 813) * 4;
        f32x4 val;
#pragma unroll
        for (int j = 0; j < 4; ++j) {
            int o = off + j;
            int v_ = o / 3, p_ = o - v_ * 3;
            val[j] = sC[(bl * 3 + p_) * SCW + v_];
        }
        __builtin_nontemporal_store(val, (f32x4*)(outp + (size_t)f * 4));
    }

    // phase 4: joints for the 4 batches
    if (t < 252) {
        int bl = t / 63;
        int rem = t - bl * 63;
        int j = rem / 3;
        int c = rem - j * 3;
        const unsigned short* Ar = &sAb[(bl * 3 + c) * 64];
        const float* Mj = Mfinal + j * 64;
        float acc = 0.f;
#pragma unroll
        for (int k = 0; k < 16; ++k) {
            float4 m = *(const float4*)&Mj[k * 4];
            acc += bf2f(Ar[k * 4 + 0]) * m.x + bf2f(Ar[k * 4 + 1]) * m.y +
                   bf2f(Ar[k * 4 + 2]) * m.z + bf2f(Ar[k * 4 + 3]) * m.w;
        }
        __builtin_nontemporal_store(acc, jout + (size_t)(b0 + bl) * 63 + rem);
    }
}

extern "C" void kernel_launch(void* const* d_in, const int* in_sizes, int n_in,
                              void* d_out, int out_size, void* d_ws, size_t ws_size,
                              hipStream_t stream) {
    const float* theta = (const float*)d_in[1];
    const float* wrist = (const float*)d_in[2];
    const float* vtpl  = (const float*)d_in[3];
    const float* jreg  = (const float*)d_in[4];
    const float* hc    = (const float*)d_in[5];
    const float* hm    = (const float*)d_in[6];
    const float* wts   = (const float*)d_in[7];
    int B = in_sizes[1] / 45;  // 4096

    float* euler_ws = (float*)d_ws;                       // B*45 f32
    float* Mfinal   = euler_ws + (size_t)B * 45;          // 1344 f32
    unsigned short* Gbf = (unsigned short*)(Mfinal + 1344);  // NVPAD*64 u16
    float* verts  = (float*)d_out;
    float* jout   = verts + (size_t)B * NV * 3;

    int nE = (B * 45 + 255) / 256;   // 720
    prep_kernel<<<nE + 336 + 272, 256, 0, stream>>>(
        theta, hc, hm, vtpl, jreg, wts, euler_ws, Mfinal, Gbf, B, nE);
    verts_kernel<<<B / 4, 256, 0, stream>>>(
        wrist, euler_ws, Mfinal, Gbf, verts, jout);
}